// Round 17
// baseline (1129.212 us; speedup 1.0000x reference)
//
#include <hip/hip_runtime.h>
#include <hip/hip_bf16.h>

// MPNN GNN: V=12500 (feat 32), E=200000 (feat 16), H=32, 6 steps.
// msg[e,o] = sum_k a[e,k]*T[src[e],k,o] + Tb[src[e],o],  a loop-invariant.
// R17: TB 512->1024, TPW 2->1 (CAP=256 unchanged). T-phase j-split refines to
// one j per thread (jg=t>>7 in 0..7) — still bijective, w2 loads still
// disjoint + quad-coalesced (R14 mapping preserved: tl in low bits). Edge
// phase: 16 waves x 1 tile. VGPR drops (acc 16->8) => 2 blocks/CU x 16 waves
// = 32 waves/CU (100% cap) vs R16's ~22 — attacks the 55us/step stall term
// (R16: VALU 44%, HBM 12%, Mfma 2.5%, Occ 35% => latency-bound).
// Proven stack: split-bf16 3-GEMM MFMA (absmax 0.0156), kc-streamed 32KB T,
// j-split zero-redundancy w2 loads (R14), hidden LDS write conflict (R15/16),
// dense edgebuild + pose scatter (R12), one atomic per real (e,o),
// agg-rezero fused in k_agru (R16).

#define NB 8   // src nodes per k_step block
#define CAP 256  // padded slots per chunk (16 waves x 16)

typedef __attribute__((ext_vector_type(8))) short bf16x8;
typedef __attribute__((ext_vector_type(4))) float f32x4;
typedef unsigned short ushort_t;

// ---------------- node projection: h = relu(nf@w1+b1)@w2+b2 ----------------
__global__ __launch_bounds__(256) void k_proj(
    const float* __restrict__ nf, const float* __restrict__ w1,
    const float* __restrict__ b1, const float* __restrict__ w2,
    const float* __restrict__ b2, float* __restrict__ hseq, int nV) {
  __shared__ float sw1[1024], sw2[1024], sb1[32], sb2[32];
  __shared__ float sx[8][32], st1[8][32];
  int t = threadIdx.x;
  int v0 = blockIdx.x * 8;
  for (int i = t; i < 1024; i += 256) { sw1[i] = w1[i]; sw2[i] = w2[i]; }
  if (t < 32) { sb1[t] = b1[t]; sb2[t] = b2[t]; }
  {
    int g = v0 * 32 + t;
    sx[t >> 5][t & 31] = (g < nV * 32) ? nf[g] : 0.f;
  }
  __syncthreads();
  int n = t >> 5, j = t & 31;
  float s = sb1[j];
#pragma unroll
  for (int i = 0; i < 32; i++) s += sx[n][i] * sw1[i * 32 + j];
  st1[n][j] = fmaxf(s, 0.f);
  __syncthreads();
  float h = sb2[j];
#pragma unroll
  for (int i = 0; i < 32; i++) h += st1[n][i] * sw2[i * 32 + j];
  if (v0 + n < nV) hseq[(size_t)(v0 + n) * 32 + j] = h;
}

// ---------------- CSR by src, padded to multiples of 16 --------------------
__global__ __launch_bounds__(256) void k_count(const int* __restrict__ key,
                                               int* __restrict__ counts, int nE) {
  int e = blockIdx.x * 256 + threadIdx.x;
  if (e < nE) atomicAdd(&counts[key[e]], 1);
}

__global__ __launch_bounds__(1024) void k_scan(const int* __restrict__ counts,
                                               int* __restrict__ row_ptr, int nV) {
  __shared__ int buf[1024];
  __shared__ int s_off;
  int t = threadIdx.x;
  if (t == 0) s_off = 0;
  __syncthreads();
  for (int base = 0; base < nV; base += 1024) {
    int x = (base + t < nV) ? ((counts[base + t] + 15) & ~15) : 0;  // pad to 16
    buf[t] = x;
    __syncthreads();
    for (int d = 1; d < 1024; d <<= 1) {
      int v2 = (t >= d) ? buf[t - d] : 0;
      __syncthreads();
      buf[t] += v2;
      __syncthreads();
    }
    int incl = buf[t];
    int off = s_off;
    __syncthreads();
    if (base + t < nV) row_ptr[base + t] = off + incl - x;  // exclusive
    if (t == 1023) s_off = off + incl;
    __syncthreads();
  }
  if (t == 0) row_ptr[nV] = s_off;
}

__global__ __launch_bounds__(256) void k_copy(const int* __restrict__ row_ptr,
                                              int* __restrict__ cursor, int nV) {
  int v = blockIdx.x * 256 + threadIdx.x;
  if (v < nV) cursor[v] = row_ptr[v];
}

// scatter: pose[e]=padded slot of edge e; dstp[slot]=dst (pads stay -1)
__global__ __launch_bounds__(256) void k_scatter(const int* __restrict__ key,
                                                 const int* __restrict__ dst,
                                                 int* __restrict__ cursor,
                                                 int* __restrict__ pose,
                                                 int* __restrict__ dstp, int nE) {
  int e = blockIdx.x * 256 + threadIdx.x;
  if (e < nE) {
    int p = atomicAdd(&cursor[key[e]], 1);
    pose[e] = p;
    dstp[p] = dst[e];
  }
}

// ------- edge MLP, dense over real edges -> split bf16 planes --------------
__global__ __launch_bounds__(256) void k_edgebuild(
    const float* __restrict__ ef, const float* __restrict__ w1,
    const float* __restrict__ b1, const int* __restrict__ pose,
    ushort_t* __restrict__ aq_hi, ushort_t* __restrict__ aq_lo, int nE) {
  __shared__ float sw1[16 * 128], sb1[128];
  __shared__ float sef[64][17];
  __shared__ int spos[64];
  int t = threadIdx.x;
  int e0 = blockIdx.x * 64;
  if (e0 >= nE) return;
  for (int i = t; i < 2048; i += 256) sw1[i] = w1[i];
  if (t < 128) sb1[t] = b1[t];
  for (int i = t; i < 1024; i += 256) {
    int g = e0 * 16 + i;
    sef[i >> 4][i & 15] = (g < nE * 16) ? ef[g] : 0.f;
  }
  if (t < 64) spos[t] = (e0 + t < nE) ? pose[e0 + t] : 0;
  __syncthreads();
  int c = t & 127;
#pragma unroll 1
  for (int it = 0; it < 32; ++it) {
    int el = it * 2 + (t >> 7);
    if (e0 + el < nE) {
      float s = sb1[c];
#pragma unroll
      for (int i = 0; i < 16; i++) s += sef[el][i] * sw1[i * 128 + c];
      s = fmaxf(s, 0.f);
      unsigned u = __float_as_uint(s);
      unsigned hb = u >> 16;
      float fh = __uint_as_float(hb << 16);
      unsigned lb = __float_as_uint(s - fh) >> 16;
      size_t p = (size_t)spos[el] * 128 + c;
      aq_hi[p] = (ushort_t)hb;
      aq_lo[p] = (ushort_t)lb;
    }
  }
}

// ---------------- per-step: kc-streamed T (j-split) + MFMA edges -----------
// LDS sTq (32 KB): quarter frags, ushort[(n*4 + h*2 + sp)*512 + l*8 + j]
//   = T[n][kc*32 + (l>>4)*8 + j][(l&15)+16h], sp: 0=hi 1=lo.
// T-phase thread map (R17): jg=t>>7 (single j), th=(t>>6)&1, tl=t&63 — same
// low-bit lane layout as R14 (quads read consecutive w2 bytes); 1024 threads
// cover the 1024 (j,th,tl) slots bijectively, w2 loads disjoint.
__global__ __launch_bounds__(1024) void k_step(
    const float* __restrict__ hseq, const float* __restrict__ w2,
    const float* __restrict__ b2, const ushort_t* __restrict__ aq_hi,
    const ushort_t* __restrict__ aq_lo, const int* __restrict__ rp16,
    const int* __restrict__ dstp, float* __restrict__ agg, int nV) {
  __shared__ unsigned short sTq[16384];  // 32 KB
  __shared__ float sh[NB][32];
  __shared__ float sTb[NB][32];
  __shared__ int s_rp[NB + 1];
  int t = threadIdx.x;
  int v0 = blockIdx.x * NB;
  if (t <= NB) {
    int v = v0 + t;
    if (v > nV) v = nV;
    s_rp[t] = rp16[v];
  }
  if (t < NB * 32) {
    int n = t >> 5, v = v0 + n;
    sh[n][t & 31] = (v < nV) ? hseq[(size_t)v * 32 + (t & 31)] : 0.f;
  }
  __syncthreads();
  int beg = s_rp[0], end = s_rp[NB];
  if (beg == end) return;  // block-uniform

  if (t < NB * 32) {  // Tb[n][o] = sum_i h[n][i]*e_b2[i*32+o]
    int n = t >> 5, o = t & 31;
    float s = 0.f;
#pragma unroll
    for (int i = 0; i < 32; i++) s += sh[n][i] * b2[i * 32 + o];
    sTb[n][o] = s;
  }

  // thread constants — edge phase (16 waves, 1 tile each)
  int wid = t >> 6, l = t & 63;
  int r = l & 15, kg = (l >> 4) << 3;
  // thread constants — T phase (j-split, one j per thread; R14 lane layout)
  int jg = t >> 7;                  // 0..7: owns j = jg
  int th = (t >> 6) & 1;            // h half
  int tl = t & 63;                  // fragment lane
  int tc = (tl & 15) + th * 16;     // output column c
  int tkr = (tl >> 4) << 3;         // k row-group offset

  int nrun = 0;  // monotonic node cursor for this wave's tile
  for (int cbase = beg; cbase < end; cbase += CAP) {
    int tn0 = NB - 1;
    int idx16 = cbase + wid * 16;
    if (idx16 < end) {
      while (idx16 >= s_rp[nrun + 1]) nrun++;
      tn0 = nrun;
    }
    f32x4 acc0 = {0.f, 0.f, 0.f, 0.f}, acc1 = {0.f, 0.f, 0.f, 0.f};

#pragma unroll 1
    for (int kc = 0; kc < 4; kc++) {
      __syncthreads();  // protect sTq from previous phase's readers
      // ---- T-quarter, j-split: disjoint w2 loads ----
      {
        int kbase = kc * 32 + tkr + jg;
        const float* wb = w2 + (size_t)kbase * 1024 + tc;  // + i*32
        float a0[NB];
#pragma unroll
        for (int n = 0; n < NB; n++) a0[n] = 0.f;
#pragma unroll 4
        for (int i = 0; i < 32; i++) {
          float w0 = wb[i * 32];
#pragma unroll
          for (int n = 0; n < NB; n++) a0[n] += sh[n][i] * w0;
        }
#pragma unroll
        for (int n = 0; n < NB; n++) {
          float x0 = a0[n];
          unsigned h0 = __float_as_uint(x0) >> 16;
          unsigned l0 = __float_as_uint(x0 - __uint_as_float(h0 << 16)) >> 16;
          int ub = ((n * 4 + th * 2) * 64 + tl) * 8 + jg;
          sTq[ub] = (ushort_t)h0;        // sp=0 (hi)
          sTq[ub + 512] = (ushort_t)l0;  // sp=1 (lo)
        }
      }
      __syncthreads();
      // ---- edge MFMA for this kc on this wave's tile ----
      if (idx16 < end) {
        const ushort_t* ah = aq_hi + (size_t)(idx16 + r) * 128 + kc * 32 + kg;
        const ushort_t* al = aq_lo + (size_t)(idx16 + r) * 128 + kc * 32 + kg;
        bf16x8 Ah = *(const bf16x8*)ah;
        bf16x8 Al = *(const bf16x8*)al;
        int b = tn0 * 2048 + l * 8;
        bf16x8 B0h = *(const bf16x8*)&sTq[b];
        bf16x8 B0l = *(const bf16x8*)&sTq[b + 512];
        bf16x8 B1h = *(const bf16x8*)&sTq[b + 1024];
        bf16x8 B1l = *(const bf16x8*)&sTq[b + 1536];
        acc0 = __builtin_amdgcn_mfma_f32_16x16x32_bf16(Ah, B0h, acc0, 0, 0, 0);
        acc0 = __builtin_amdgcn_mfma_f32_16x16x32_bf16(Al, B0h, acc0, 0, 0, 0);
        acc0 = __builtin_amdgcn_mfma_f32_16x16x32_bf16(Ah, B0l, acc0, 0, 0, 0);
        acc1 = __builtin_amdgcn_mfma_f32_16x16x32_bf16(Ah, B1h, acc1, 0, 0, 0);
        acc1 = __builtin_amdgcn_mfma_f32_16x16x32_bf16(Al, B1h, acc1, 0, 0, 0);
        acc1 = __builtin_amdgcn_mfma_f32_16x16x32_bf16(Ah, B1l, acc1, 0, 0, 0);
      }
    }
    // ---- flush: one atomic per real (e,o) ----
    if (idx16 < end) {
      int er = (l >> 4) << 2;
      int c = l & 15;
#pragma unroll
      for (int j = 0; j < 4; j++) {
        int idx = idx16 + er + j;
        int d = dstp[idx];
        if (d >= 0) {
          atomicAdd(&agg[(size_t)d * 32 + c], acc0[j] + sTb[tn0][c]);
          atomicAdd(&agg[(size_t)d * 32 + c + 16], acc1[j] + sTb[tn0][c + 16]);
        }
      }
    }
  }
}

// ------- fused agg-read + GRU + agg-rezero: block = 8 nodes x 32 o ---------
__global__ __launch_bounds__(256) void k_agru(
    float* __restrict__ agg, const float* __restrict__ cbias,
    const float* __restrict__ wih, const float* __restrict__ whh,
    const float* __restrict__ bih, const float* __restrict__ bhh,
    float* __restrict__ hseq, int nV) {
  __shared__ float swT[2][32 * 97];
  __shared__ float sb[2][96], scb[32];
  __shared__ float sx[8][32], shd[8][32];
  int t = threadIdx.x;
  int v0 = blockIdx.x * 8;
  for (int idx = t; idx < 3072; idx += 256) {
    int row = idx >> 5, i = idx & 31;
    swT[0][i * 97 + row] = wih[idx];
    swT[1][i * 97 + row] = whh[idx];
  }
  if (t < 96) { sb[0][t] = bih[t]; sb[1][t] = bhh[t]; }
  if (t < 32) scb[t] = cbias[t];
  {
    int n = t >> 5, v = v0 + n, j = t & 31;
    shd[n][j] = (v < nV) ? hseq[(size_t)v * 32 + j] : 0.f;
    float av = 0.f;
    if (v < nV) {
      av = agg[(size_t)v * 32 + j];
      agg[(size_t)v * 32 + j] = 0.f;  // re-zero for next step's atomics
    }
    sx[n][j] = (v < nV) ? fmaxf(av + cbias[j], 0.f) : 0.f;
  }
  __syncthreads();
  int n = t >> 5, o = t & 31;
  int v = v0 + n;
  if (v >= nV) return;
  float gir = sb[0][o], giz = sb[0][32 + o], gin = sb[0][64 + o];
  float ghr = sb[1][o], ghz = sb[1][32 + o], ghn = sb[1][64 + o];
#pragma unroll
  for (int i = 0; i < 32; i++) {
    float xi = sx[n][i], hi = shd[n][i];
    gir += xi * swT[0][i * 97 + o];
    giz += xi * swT[0][i * 97 + 32 + o];
    gin += xi * swT[0][i * 97 + 64 + o];
    ghr += hi * swT[1][i * 97 + o];
    ghz += hi * swT[1][i * 97 + 32 + o];
    ghn += hi * swT[1][i * 97 + 64 + o];
  }
  float r = 1.f / (1.f + __expf(-(gir + ghr)));
  float z = 1.f / (1.f + __expf(-(giz + ghz)));
  float ng = tanhf(gin + r * ghn);
  hseq[(size_t)v * 32 + o] = (1.f - z) * ng + z * shd[n][o];
}

// ---------------- decoder: out = relu(h@dw1+db1)@dw2+db2  (V x 64) ---------
__global__ __launch_bounds__(256) void k_dec(
    const float* __restrict__ hseq, const float* __restrict__ w1,
    const float* __restrict__ b1, const float* __restrict__ w2,
    const float* __restrict__ b2, float* __restrict__ out, int nV) {
  __shared__ float sw1[1024], sb1[32], sw2[2048], sb2[64];
  __shared__ float sx[4][32], st1[4][32];
  int t = threadIdx.x;
  int v0 = blockIdx.x * 4;
  for (int i = t; i < 1024; i += 256) sw1[i] = w1[i];
  for (int i = t; i < 2048; i += 256) sw2[i] = w2[i];
  if (t < 32) sb1[t] = b1[t];
  if (t < 64) sb2[t] = b2[t];
  if (t < 128) {
    int g = v0 * 32 + t;
    sx[t >> 5][t & 31] = (g < nV * 32) ? hseq[g] : 0.f;
  }
  __syncthreads();
  if (t < 128) {
    int n = t >> 5, j = t & 31;
    float s = sb1[j];
#pragma unroll
    for (int i = 0; i < 32; i++) s += sx[n][i] * sw1[i * 32 + j];
    st1[n][j] = fmaxf(s, 0.f);
  }
  __syncthreads();
  int n = t >> 6, j = t & 63;
  float s = sb2[j];
#pragma unroll
  for (int i = 0; i < 32; i++) s += st1[n][i] * sw2[i * 64 + j];
  if (v0 + n < nV) out[(size_t)(v0 + n) * 64 + j] = s;
}

extern "C" void kernel_launch(void* const* d_in, const int* in_sizes, int n_in,
                              void* d_out, int out_size, void* d_ws, size_t ws_size,
                              hipStream_t stream) {
  const float* node_feats = (const float*)d_in[0];
  const float* edge_feats = (const float*)d_in[1];
  const int* src = (const int*)d_in[2];
  const int* dst = (const int*)d_in[3];
  const float* proj_w1 = (const float*)d_in[4];
  const float* proj_b1 = (const float*)d_in[5];
  const float* proj_w2 = (const float*)d_in[6];
  const float* proj_b2 = (const float*)d_in[7];
  const float* e_w1 = (const float*)d_in[8];
  const float* e_b1 = (const float*)d_in[9];
  const float* e_w2 = (const float*)d_in[10];
  const float* e_b2 = (const float*)d_in[11];
  const float* conv_bias = (const float*)d_in[12];
  const float* gru_wih = (const float*)d_in[13];
  const float* gru_whh = (const float*)d_in[14];
  const float* gru_bih = (const float*)d_in[15];
  const float* gru_bhh = (const float*)d_in[16];
  const float* dec_w1 = (const float*)d_in[17];
  const float* dec_b1 = (const float*)d_in[18];
  const float* dec_w2 = (const float*)d_in[19];
  const float* dec_b2 = (const float*)d_in[20];
  float* out = (float*)d_out;

  const int nV = in_sizes[0] / 32;
  const int nE = in_sizes[2];
  // worst-case 16-padded idx space
  const int S = (nE + 15 * nV + 255) & ~255;

  // workspace carve-up (~206 MB worst case; proven-safe ~208)
  char* base = (char*)d_ws;
  size_t off = 0;
  auto carve = [&](size_t bytes) {
    void* r = base + off;
    off = (off + bytes + 255) & ~(size_t)255;
    return r;
  };
  ushort_t* aq_hi = (ushort_t*)carve((size_t)S * 128 * 2);
  ushort_t* aq_lo = (ushort_t*)carve((size_t)S * 128 * 2);
  float* hseq = (float*)carve((size_t)nV * 32 * 4);
  float* agg = (float*)carve((size_t)nV * 32 * 4);
  int* countsS = (int*)carve((size_t)nV * 4);
  int* rp16 = (int*)carve((size_t)(nV + 1) * 4);
  int* curS = (int*)carve((size_t)nV * 4);
  int* pose = (int*)carve((size_t)nE * 4);
  int* dstp = (int*)carve((size_t)S * 4);
  (void)ws_size;

  const int TB = 256;
  int gE = (nE + TB - 1) / TB;
  int g8 = (nV + 7) / 8;
  int g4 = (nV + 3) / 4;
  int gStep = (nV + NB - 1) / NB;

  // setup
  k_proj<<<g8, TB, 0, stream>>>(node_feats, proj_w1, proj_b1, proj_w2, proj_b2, hseq, nV);
  hipMemsetAsync(countsS, 0, (size_t)nV * 4, stream);
  hipMemsetAsync(dstp, 0xFF, (size_t)S * 4, stream);  // -1 sentinels
  hipMemsetAsync(agg, 0, (size_t)nV * 32 * 4, stream);  // covers 0xAA poison
  k_count<<<gE, TB, 0, stream>>>(src, countsS, nE);
  k_scan<<<1, 1024, 0, stream>>>(countsS, rp16, nV);
  k_copy<<<(nV + TB - 1) / TB, TB, 0, stream>>>(rp16, curS, nV);
  k_scatter<<<gE, TB, 0, stream>>>(src, dst, curS, pose, dstp, nE);
  k_edgebuild<<<(nE + 63) / 64, TB, 0, stream>>>(edge_feats, e_w1, e_b1, pose,
                                                 aq_hi, aq_lo, nE);

  // 6 message-passing steps (k_agru re-zeroes agg for the next step)
  for (int step = 0; step < 6; step++) {
    k_step<<<gStep, 1024, 0, stream>>>(hseq, e_w2, e_b2, aq_hi, aq_lo, rp16, dstp,
                                       agg, nV);
    k_agru<<<g8, TB, 0, stream>>>(agg, conv_bias, gru_wih, gru_whh,
                                  gru_bih, gru_bhh, hseq, nV);
  }

  // decoder
  k_dec<<<g4, TB, 0, stream>>>(hseq, dec_w1, dec_b1, dec_w2, dec_b2, out, nV);
}

// Round 18
// 842.886 us; speedup vs baseline: 1.3397x; 1.3397x over previous
//
#include <hip/hip_runtime.h>
#include <hip/hip_bf16.h>

// MPNN GNN: V=12500 (feat 32), E=200000 (feat 16), H=32, 6 steps.
// msg[e,o] = sum_k a[e,k]*T[src[e],k,o] + Tb[src[e],o],  a loop-invariant.
// R18: R16 config exactly (proven 117us/step; R17's 1024-thr and R15's remap
// both regressed) + ONE change: T-phase reads h via transposed sh_t[32][8]
// as 2x ds_read_b128 per i instead of 8x ds_read_b32 — cuts T-phase LDS
// wave-instr 4x (8192 -> 2048 per block), attacking the LDS-pipe occupancy
// identified as the dominant hidden stall term.
// Proven stack: split-bf16 3-GEMM MFMA (absmax 0.0156), kc-streamed 32KB T,
// j-split zero-redundancy w2 loads (R14 map: quads read consecutive bytes;
// stride-16B LDS write 8-way conflict is measured fully-hidden), dense
// edgebuild + pose scatter, one atomic per real (e,o), agg-rezero in k_agru.

#define NB 8   // src nodes per k_step block
#define TPW 2  // 16-edge tiles per wave per chunk
#define CAP (8 * TPW * 16)  // 256 padded slots per chunk

typedef __attribute__((ext_vector_type(8))) short bf16x8;
typedef __attribute__((ext_vector_type(4))) float f32x4;
typedef unsigned short ushort_t;

// ---------------- node projection: h = relu(nf@w1+b1)@w2+b2 ----------------
__global__ __launch_bounds__(256) void k_proj(
    const float* __restrict__ nf, const float* __restrict__ w1,
    const float* __restrict__ b1, const float* __restrict__ w2,
    const float* __restrict__ b2, float* __restrict__ hseq, int nV) {
  __shared__ float sw1[1024], sw2[1024], sb1[32], sb2[32];
  __shared__ float sx[8][32], st1[8][32];
  int t = threadIdx.x;
  int v0 = blockIdx.x * 8;
  for (int i = t; i < 1024; i += 256) { sw1[i] = w1[i]; sw2[i] = w2[i]; }
  if (t < 32) { sb1[t] = b1[t]; sb2[t] = b2[t]; }
  {
    int g = v0 * 32 + t;
    sx[t >> 5][t & 31] = (g < nV * 32) ? nf[g] : 0.f;
  }
  __syncthreads();
  int n = t >> 5, j = t & 31;
  float s = sb1[j];
#pragma unroll
  for (int i = 0; i < 32; i++) s += sx[n][i] * sw1[i * 32 + j];
  st1[n][j] = fmaxf(s, 0.f);
  __syncthreads();
  float h = sb2[j];
#pragma unroll
  for (int i = 0; i < 32; i++) h += st1[n][i] * sw2[i * 32 + j];
  if (v0 + n < nV) hseq[(size_t)(v0 + n) * 32 + j] = h;
}

// ---------------- CSR by src, padded to multiples of 16 --------------------
__global__ __launch_bounds__(256) void k_count(const int* __restrict__ key,
                                               int* __restrict__ counts, int nE) {
  int e = blockIdx.x * 256 + threadIdx.x;
  if (e < nE) atomicAdd(&counts[key[e]], 1);
}

__global__ __launch_bounds__(1024) void k_scan(const int* __restrict__ counts,
                                               int* __restrict__ row_ptr, int nV) {
  __shared__ int buf[1024];
  __shared__ int s_off;
  int t = threadIdx.x;
  if (t == 0) s_off = 0;
  __syncthreads();
  for (int base = 0; base < nV; base += 1024) {
    int x = (base + t < nV) ? ((counts[base + t] + 15) & ~15) : 0;  // pad to 16
    buf[t] = x;
    __syncthreads();
    for (int d = 1; d < 1024; d <<= 1) {
      int v2 = (t >= d) ? buf[t - d] : 0;
      __syncthreads();
      buf[t] += v2;
      __syncthreads();
    }
    int incl = buf[t];
    int off = s_off;
    __syncthreads();
    if (base + t < nV) row_ptr[base + t] = off + incl - x;  // exclusive
    if (t == 1023) s_off = off + incl;
    __syncthreads();
  }
  if (t == 0) row_ptr[nV] = s_off;
}

__global__ __launch_bounds__(256) void k_copy(const int* __restrict__ row_ptr,
                                              int* __restrict__ cursor, int nV) {
  int v = blockIdx.x * 256 + threadIdx.x;
  if (v < nV) cursor[v] = row_ptr[v];
}

// scatter: pose[e]=padded slot of edge e; dstp[slot]=dst (pads stay -1)
__global__ __launch_bounds__(256) void k_scatter(const int* __restrict__ key,
                                                 const int* __restrict__ dst,
                                                 int* __restrict__ cursor,
                                                 int* __restrict__ pose,
                                                 int* __restrict__ dstp, int nE) {
  int e = blockIdx.x * 256 + threadIdx.x;
  if (e < nE) {
    int p = atomicAdd(&cursor[key[e]], 1);
    pose[e] = p;
    dstp[p] = dst[e];
  }
}

// ------- edge MLP, dense over real edges -> split bf16 planes --------------
__global__ __launch_bounds__(256) void k_edgebuild(
    const float* __restrict__ ef, const float* __restrict__ w1,
    const float* __restrict__ b1, const int* __restrict__ pose,
    ushort_t* __restrict__ aq_hi, ushort_t* __restrict__ aq_lo, int nE) {
  __shared__ float sw1[16 * 128], sb1[128];
  __shared__ float sef[64][17];
  __shared__ int spos[64];
  int t = threadIdx.x;
  int e0 = blockIdx.x * 64;
  if (e0 >= nE) return;
  for (int i = t; i < 2048; i += 256) sw1[i] = w1[i];
  if (t < 128) sb1[t] = b1[t];
  for (int i = t; i < 1024; i += 256) {
    int g = e0 * 16 + i;
    sef[i >> 4][i & 15] = (g < nE * 16) ? ef[g] : 0.f;
  }
  if (t < 64) spos[t] = (e0 + t < nE) ? pose[e0 + t] : 0;
  __syncthreads();
  int c = t & 127;
#pragma unroll 1
  for (int it = 0; it < 32; ++it) {
    int el = it * 2 + (t >> 7);
    if (e0 + el < nE) {
      float s = sb1[c];
#pragma unroll
      for (int i = 0; i < 16; i++) s += sef[el][i] * sw1[i * 128 + c];
      s = fmaxf(s, 0.f);
      unsigned u = __float_as_uint(s);
      unsigned hb = u >> 16;
      float fh = __uint_as_float(hb << 16);
      unsigned lb = __float_as_uint(s - fh) >> 16;
      size_t p = (size_t)spos[el] * 128 + c;
      aq_hi[p] = (ushort_t)hb;
      aq_lo[p] = (ushort_t)lb;
    }
  }
}

// ---------------- per-step: kc-streamed T (j-split) + MFMA edges -----------
// LDS sTq (32 KB): quarter frags, ushort[(n*4 + h*2 + sp)*512 + l*8 + j]
//   = T[n][kc*32 + (l>>4)*8 + j][(l&15)+16h], sp: 0=hi 1=lo.
// T-phase thread map (R14/R16 proven): jg=t>>7, th=(t>>6)&1, tl=t&63.
// R18: h read via transposed sh_t[32][8] -> 2x ds_read_b128 per i.
__global__ __launch_bounds__(512) void k_step(
    const float* __restrict__ hseq, const float* __restrict__ w2,
    const float* __restrict__ b2, const ushort_t* __restrict__ aq_hi,
    const ushort_t* __restrict__ aq_lo, const int* __restrict__ rp16,
    const int* __restrict__ dstp, float* __restrict__ agg, int nV) {
  __shared__ unsigned short sTq[16384];  // 32 KB
  __shared__ float sh[NB][32];     // [n][i] — Tb phase
  __shared__ float sh_t[32][NB];   // [i][n] — T phase (b128-readable)
  __shared__ float sTb[NB][32];
  __shared__ int s_rp[NB + 1];
  int t = threadIdx.x;
  int v0 = blockIdx.x * NB;
  if (t <= NB) {
    int v = v0 + t;
    if (v > nV) v = nV;
    s_rp[t] = rp16[v];
  }
  if (t < NB * 32) {
    int n = t >> 5, i = t & 31, v = v0 + n;
    float hv = (v < nV) ? hseq[(size_t)v * 32 + i] : 0.f;
    sh[n][i] = hv;
    sh_t[i][n] = hv;
  }
  __syncthreads();
  int beg = s_rp[0], end = s_rp[NB];
  if (beg == end) return;  // block-uniform

  if (t < NB * 32) {  // Tb[n][o] = sum_i h[n][i]*e_b2[i*32+o]
    int n = t >> 5, o = t & 31;
    float s = 0.f;
#pragma unroll
    for (int i = 0; i < 32; i++) s += sh[n][i] * b2[i * 32 + o];
    sTb[n][o] = s;
  }

  // thread constants — edge phase
  int wid = t >> 6, l = t & 63;
  int r = l & 15, kg = (l >> 4) << 3;
  // thread constants — T phase (j-split, R14 mapping)
  int jg = t >> 7;                  // 0..3: owns j = {2jg, 2jg+1}
  int th = (t >> 6) & 1;            // h half
  int tl = t & 63;                  // fragment lane
  int tc = (tl & 15) + th * 16;     // output column c
  int tkr = (tl >> 4) << 3;         // k row-group offset

  int nrun = 0;  // monotonic node cursor for this wave's tiles
  for (int cbase = beg; cbase < end; cbase += CAP) {
    int tn[TPW];
#pragma unroll
    for (int ti = 0; ti < TPW; ti++) {
      int idx16 = cbase + (wid * TPW + ti) * 16;
      if (idx16 < end) {
        while (idx16 >= s_rp[nrun + 1]) nrun++;
        tn[ti] = nrun;
      } else
        tn[ti] = NB - 1;
    }
    f32x4 acc[TPW][2];
#pragma unroll
    for (int ti = 0; ti < TPW; ti++)
#pragma unroll
      for (int hh = 0; hh < 2; hh++) acc[ti][hh] = (f32x4){0.f, 0.f, 0.f, 0.f};

#pragma unroll 1
    for (int kc = 0; kc < 4; kc++) {
      __syncthreads();  // protect sTq from previous phase's readers
      // ---- T-quarter, j-split: disjoint w2 loads; b128 h reads ----
      {
        int kbase = kc * 32 + tkr + 2 * jg;
        const float* wb = w2 + (size_t)kbase * 1024 + tc;  // + jj*1024 + i*32
        float a0[NB], a1[NB];
#pragma unroll
        for (int n = 0; n < NB; n++) { a0[n] = 0.f; a1[n] = 0.f; }
#pragma unroll 4
        for (int i = 0; i < 32; i++) {
          float w0 = wb[i * 32];
          float w1 = wb[1024 + i * 32];
          float4 sA = *(const float4*)&sh_t[i][0];
          float4 sB = *(const float4*)&sh_t[i][4];
          a0[0] += sA.x * w0; a1[0] += sA.x * w1;
          a0[1] += sA.y * w0; a1[1] += sA.y * w1;
          a0[2] += sA.z * w0; a1[2] += sA.z * w1;
          a0[3] += sA.w * w0; a1[3] += sA.w * w1;
          a0[4] += sB.x * w0; a1[4] += sB.x * w1;
          a0[5] += sB.y * w0; a1[5] += sB.y * w1;
          a0[6] += sB.z * w0; a1[6] += sB.z * w1;
          a0[7] += sB.w * w0; a1[7] += sB.w * w1;
        }
#pragma unroll
        for (int n = 0; n < NB; n++) {
          float x0 = a0[n], x1 = a1[n];
          unsigned h0 = __float_as_uint(x0) >> 16, h1 = __float_as_uint(x1) >> 16;
          unsigned l0 = __float_as_uint(x0 - __uint_as_float(h0 << 16)) >> 16;
          unsigned l1 = __float_as_uint(x1 - __uint_as_float(h1 << 16)) >> 16;
          int ub = ((n * 4 + th * 2) * 64 + tl) * 8 + 2 * jg;
          *(unsigned*)&sTq[ub] = h0 | (h1 << 16);        // sp=0 (hi)
          *(unsigned*)&sTq[ub + 512] = l0 | (l1 << 16);  // sp=1 (lo)
        }
      }
      __syncthreads();
      // ---- edge MFMA for this kc on TPW tiles ----
#pragma unroll
      for (int ti = 0; ti < TPW; ti++) {
        int idx16 = cbase + (wid * TPW + ti) * 16;
        if (idx16 < end) {
          const ushort_t* ah = aq_hi + (size_t)(idx16 + r) * 128 + kc * 32 + kg;
          const ushort_t* al = aq_lo + (size_t)(idx16 + r) * 128 + kc * 32 + kg;
          bf16x8 Ah = *(const bf16x8*)ah;
          bf16x8 Al = *(const bf16x8*)al;
          int b = tn[ti] * 2048 + l * 8;
          bf16x8 B0h = *(const bf16x8*)&sTq[b];
          bf16x8 B0l = *(const bf16x8*)&sTq[b + 512];
          bf16x8 B1h = *(const bf16x8*)&sTq[b + 1024];
          bf16x8 B1l = *(const bf16x8*)&sTq[b + 1536];
          acc[ti][0] = __builtin_amdgcn_mfma_f32_16x16x32_bf16(Ah, B0h, acc[ti][0], 0, 0, 0);
          acc[ti][0] = __builtin_amdgcn_mfma_f32_16x16x32_bf16(Al, B0h, acc[ti][0], 0, 0, 0);
          acc[ti][0] = __builtin_amdgcn_mfma_f32_16x16x32_bf16(Ah, B0l, acc[ti][0], 0, 0, 0);
          acc[ti][1] = __builtin_amdgcn_mfma_f32_16x16x32_bf16(Ah, B1h, acc[ti][1], 0, 0, 0);
          acc[ti][1] = __builtin_amdgcn_mfma_f32_16x16x32_bf16(Al, B1h, acc[ti][1], 0, 0, 0);
          acc[ti][1] = __builtin_amdgcn_mfma_f32_16x16x32_bf16(Ah, B1l, acc[ti][1], 0, 0, 0);
        }
      }
    }
    // ---- flush: one atomic per real (e,o) ----
    int er = (l >> 4) << 2;
    int c = l & 15;
#pragma unroll
    for (int ti = 0; ti < TPW; ti++) {
      int idx16 = cbase + (wid * TPW + ti) * 16;
      if (idx16 < end) {
#pragma unroll
        for (int j = 0; j < 4; j++) {
          int idx = idx16 + er + j;
          int d = dstp[idx];
          if (d >= 0) {
            atomicAdd(&agg[(size_t)d * 32 + c], acc[ti][0][j] + sTb[tn[ti]][c]);
            atomicAdd(&agg[(size_t)d * 32 + c + 16], acc[ti][1][j] + sTb[tn[ti]][c + 16]);
          }
        }
      }
    }
  }
}

// ------- fused agg-read + GRU + agg-rezero: block = 8 nodes x 32 o ---------
__global__ __launch_bounds__(256) void k_agru(
    float* __restrict__ agg, const float* __restrict__ cbias,
    const float* __restrict__ wih, const float* __restrict__ whh,
    const float* __restrict__ bih, const float* __restrict__ bhh,
    float* __restrict__ hseq, int nV) {
  __shared__ float swT[2][32 * 97];
  __shared__ float sb[2][96], scb[32];
  __shared__ float sx[8][32], shd[8][32];
  int t = threadIdx.x;
  int v0 = blockIdx.x * 8;
  for (int idx = t; idx < 3072; idx += 256) {
    int row = idx >> 5, i = idx & 31;
    swT[0][i * 97 + row] = wih[idx];
    swT[1][i * 97 + row] = whh[idx];
  }
  if (t < 96) { sb[0][t] = bih[t]; sb[1][t] = bhh[t]; }
  if (t < 32) scb[t] = cbias[t];
  {
    int n = t >> 5, v = v0 + n, j = t & 31;
    shd[n][j] = (v < nV) ? hseq[(size_t)v * 32 + j] : 0.f;
    float av = 0.f;
    if (v < nV) {
      av = agg[(size_t)v * 32 + j];
      agg[(size_t)v * 32 + j] = 0.f;  // re-zero for next step's atomics
    }
    sx[n][j] = (v < nV) ? fmaxf(av + cbias[j], 0.f) : 0.f;
  }
  __syncthreads();
  int n = t >> 5, o = t & 31;
  int v = v0 + n;
  if (v >= nV) return;
  float gir = sb[0][o], giz = sb[0][32 + o], gin = sb[0][64 + o];
  float ghr = sb[1][o], ghz = sb[1][32 + o], ghn = sb[1][64 + o];
#pragma unroll
  for (int i = 0; i < 32; i++) {
    float xi = sx[n][i], hi = shd[n][i];
    gir += xi * swT[0][i * 97 + o];
    giz += xi * swT[0][i * 97 + 32 + o];
    gin += xi * swT[0][i * 97 + 64 + o];
    ghr += hi * swT[1][i * 97 + o];
    ghz += hi * swT[1][i * 97 + 32 + o];
    ghn += hi * swT[1][i * 97 + 64 + o];
  }
  float r = 1.f / (1.f + __expf(-(gir + ghr)));
  float z = 1.f / (1.f + __expf(-(giz + ghz)));
  float ng = tanhf(gin + r * ghn);
  hseq[(size_t)v * 32 + o] = (1.f - z) * ng + z * shd[n][o];
}

// ---------------- decoder: out = relu(h@dw1+db1)@dw2+db2  (V x 64) ---------
__global__ __launch_bounds__(256) void k_dec(
    const float* __restrict__ hseq, const float* __restrict__ w1,
    const float* __restrict__ b1, const float* __restrict__ w2,
    const float* __restrict__ b2, float* __restrict__ out, int nV) {
  __shared__ float sw1[1024], sb1[32], sw2[2048], sb2[64];
  __shared__ float sx[4][32], st1[4][32];
  int t = threadIdx.x;
  int v0 = blockIdx.x * 4;
  for (int i = t; i < 1024; i += 256) sw1[i] = w1[i];
  for (int i = t; i < 2048; i += 256) sw2[i] = w2[i];
  if (t < 32) sb1[t] = b1[t];
  if (t < 64) sb2[t] = b2[t];
  if (t < 128) {
    int g = v0 * 32 + t;
    sx[t >> 5][t & 31] = (g < nV * 32) ? hseq[g] : 0.f;
  }
  __syncthreads();
  if (t < 128) {
    int n = t >> 5, j = t & 31;
    float s = sb1[j];
#pragma unroll
    for (int i = 0; i < 32; i++) s += sx[n][i] * sw1[i * 32 + j];
    st1[n][j] = fmaxf(s, 0.f);
  }
  __syncthreads();
  int n = t >> 6, j = t & 63;
  float s = sb2[j];
#pragma unroll
  for (int i = 0; i < 32; i++) s += st1[n][i] * sw2[i * 64 + j];
  if (v0 + n < nV) out[(size_t)(v0 + n) * 64 + j] = s;
}

extern "C" void kernel_launch(void* const* d_in, const int* in_sizes, int n_in,
                              void* d_out, int out_size, void* d_ws, size_t ws_size,
                              hipStream_t stream) {
  const float* node_feats = (const float*)d_in[0];
  const float* edge_feats = (const float*)d_in[1];
  const int* src = (const int*)d_in[2];
  const int* dst = (const int*)d_in[3];
  const float* proj_w1 = (const float*)d_in[4];
  const float* proj_b1 = (const float*)d_in[5];
  const float* proj_w2 = (const float*)d_in[6];
  const float* proj_b2 = (const float*)d_in[7];
  const float* e_w1 = (const float*)d_in[8];
  const float* e_b1 = (const float*)d_in[9];
  const float* e_w2 = (const float*)d_in[10];
  const float* e_b2 = (const float*)d_in[11];
  const float* conv_bias = (const float*)d_in[12];
  const float* gru_wih = (const float*)d_in[13];
  const float* gru_whh = (const float*)d_in[14];
  const float* gru_bih = (const float*)d_in[15];
  const float* gru_bhh = (const float*)d_in[16];
  const float* dec_w1 = (const float*)d_in[17];
  const float* dec_b1 = (const float*)d_in[18];
  const float* dec_w2 = (const float*)d_in[19];
  const float* dec_b2 = (const float*)d_in[20];
  float* out = (float*)d_out;

  const int nV = in_sizes[0] / 32;
  const int nE = in_sizes[2];
  // worst-case 16-padded idx space
  const int S = (nE + 15 * nV + 255) & ~255;

  // workspace carve-up (~206 MB worst case; proven-safe ~208)
  char* base = (char*)d_ws;
  size_t off = 0;
  auto carve = [&](size_t bytes) {
    void* r = base + off;
    off = (off + bytes + 255) & ~(size_t)255;
    return r;
  };
  ushort_t* aq_hi = (ushort_t*)carve((size_t)S * 128 * 2);
  ushort_t* aq_lo = (ushort_t*)carve((size_t)S * 128 * 2);
  float* hseq = (float*)carve((size_t)nV * 32 * 4);
  float* agg = (float*)carve((size_t)nV * 32 * 4);
  int* countsS = (int*)carve((size_t)nV * 4);
  int* rp16 = (int*)carve((size_t)(nV + 1) * 4);
  int* curS = (int*)carve((size_t)nV * 4);
  int* pose = (int*)carve((size_t)nE * 4);
  int* dstp = (int*)carve((size_t)S * 4);
  (void)ws_size;

  const int TB = 256;
  int gE = (nE + TB - 1) / TB;
  int g8 = (nV + 7) / 8;
  int g4 = (nV + 3) / 4;
  int gStep = (nV + NB - 1) / NB;

  // setup
  k_proj<<<g8, TB, 0, stream>>>(node_feats, proj_w1, proj_b1, proj_w2, proj_b2, hseq, nV);
  hipMemsetAsync(countsS, 0, (size_t)nV * 4, stream);
  hipMemsetAsync(dstp, 0xFF, (size_t)S * 4, stream);  // -1 sentinels
  hipMemsetAsync(agg, 0, (size_t)nV * 32 * 4, stream);  // covers 0xAA poison
  k_count<<<gE, TB, 0, stream>>>(src, countsS, nE);
  k_scan<<<1, 1024, 0, stream>>>(countsS, rp16, nV);
  k_copy<<<(nV + TB - 1) / TB, TB, 0, stream>>>(rp16, curS, nV);
  k_scatter<<<gE, TB, 0, stream>>>(src, dst, curS, pose, dstp, nE);
  k_edgebuild<<<(nE + 63) / 64, TB, 0, stream>>>(edge_feats, e_w1, e_b1, pose,
                                                 aq_hi, aq_lo, nE);

  // 6 message-passing steps (k_agru re-zeroes agg for the next step)
  for (int step = 0; step < 6; step++) {
    k_step<<<gStep, 512, 0, stream>>>(hseq, e_w2, e_b2, aq_hi, aq_lo, rp16, dstp,
                                      agg, nV);
    k_agru<<<g8, TB, 0, stream>>>(agg, conv_bias, gru_wih, gru_whh,
                                  gru_bih, gru_bhh, hseq, nV);
  }

  // decoder
  k_dec<<<g4, TB, 0, stream>>>(hseq, dec_w1, dec_b1, dec_w2, dec_b2, out, nV);
}